// Round 1
// baseline (1971.242 us; speedup 1.0000x reference)
//
#include <hip/hip_runtime.h>
#include <stdint.h>

typedef unsigned int u32;
typedef unsigned long long u64;

#define B_ 8
#define N_ 100000
#define C_ 10
#define K1_ 1000
#define N2_ (C_ * K1_)
#define NBIN 4096
#define CAP 4096
#define MIN_CONF_F 0.05f
#define NMS_IOU_F 0.4f
#define POST_IOU_F 0.65f

// ---------------------------------------------------------------------------
// Kernel 1: per-(b,c) top-1000 of masked scores, stable (value desc, idx asc).
// Two-level histogram radix-select on float bits, then bitonic sort of the
// compacted candidate set (<= ~1010 elements with this data; capacity 4096).
// ---------------------------------------------------------------------------
__global__ __launch_bounds__(256) void k_topk1(const float* __restrict__ cls,
                                               float* __restrict__ score1,
                                               int* __restrict__ idx1) {
  const int slice = blockIdx.x;  // b*C + c
  const int b = slice / C_, c = slice % C_;
  const int tid = threadIdx.x, bd = blockDim.x;

  __shared__ u32 hist[NBIN];
  __shared__ u64 buf[CAP];
  __shared__ int sh_b1;
  __shared__ u32 sh_base, sh_T, sh_cnt;

  // ---- level-1 histogram on bits[30:19] (all candidates positive floats) ----
  for (int i = tid; i < NBIN; i += bd) hist[i] = 0;
  __syncthreads();
  for (int i = tid; i < N_; i += bd) {
    float s = cls[((size_t)b * N_ + i) * C_ + c];
    if (s >= MIN_CONF_F) {
      u32 k = __float_as_uint(s);
      atomicAdd(&hist[k >> 19], 1u);
    }
  }
  __syncthreads();
  if (tid == 0) {
    u32 cum = 0;
    int b1 = -1;
    u32 base = 0;
    for (int bin = NBIN - 1; bin >= 0; --bin) {
      cum += hist[bin];
      if (cum >= (u32)K1_) { b1 = bin; base = cum - hist[bin]; break; }
    }
    sh_b1 = b1;
    sh_base = base;
    if (b1 < 0) sh_T = 0;  // fewer than K1 valid -> take all valid
  }
  __syncthreads();
  const int b1 = sh_b1;

  if (b1 >= 0) {
    // ---- level-2 histogram on bits[18:7] within boundary bin ----
    const u32 base = sh_base;
    for (int i = tid; i < NBIN; i += bd) hist[i] = 0;
    __syncthreads();
    for (int i = tid; i < N_; i += bd) {
      float s = cls[((size_t)b * N_ + i) * C_ + c];
      if (s >= MIN_CONF_F) {
        u32 k = __float_as_uint(s);
        if ((int)(k >> 19) == b1) atomicAdd(&hist[(k >> 7) & 0xFFFu], 1u);
      }
    }
    __syncthreads();
    if (tid == 0) {
      u32 cum = base;
      u32 T = ((u32)b1) << 19;
      for (int bin = NBIN - 1; bin >= 0; --bin) {
        cum += hist[bin];
        if (cum >= (u32)K1_) { T = (((u32)b1) << 19) | (((u32)bin) << 7); break; }
      }
      sh_T = T;
    }
    __syncthreads();
  }

  // ---- compact all candidates with key >= T ----
  if (tid == 0) sh_cnt = 0;
  __syncthreads();
  const u32 T = sh_T;
  for (int i = tid; i < N_; i += bd) {
    float s = cls[((size_t)b * N_ + i) * C_ + c];
    if (s >= MIN_CONF_F) {
      u32 k = __float_as_uint(s);
      if (k >= T) {
        u32 pos = atomicAdd(&sh_cnt, 1u);
        if (pos < CAP) buf[pos] = ((u64)k << 32) | (u32)(~(u32)i);
      }
    }
  }
  __syncthreads();
  u32 m = sh_cnt;
  if (m > CAP) m = CAP;
  for (int i = tid; i < CAP; i += bd)
    if ((u32)i >= m) buf[i] = 0ull;
  __syncthreads();

  // ---- bitonic sort descending (key = valbits<<32 | ~idx) ----
  for (u32 kk = 2; kk <= CAP; kk <<= 1) {
    for (u32 j = kk >> 1; j > 0; j >>= 1) {
      for (u32 i = tid; i < CAP; i += bd) {
        u32 l = i ^ j;
        if (l > i) {
          u64 a = buf[i], bb = buf[l];
          bool desc = ((i & kk) == 0);
          if (desc ? (a < bb) : (a > bb)) { buf[i] = bb; buf[l] = a; }
        }
      }
      __syncthreads();
    }
  }

  // ---- emit top K1 (padded slots -> invalid) ----
  for (int p = tid; p < K1_; p += bd) {
    u64 e = buf[p];
    u32 k = (u32)(e >> 32);
    float s;
    int oi;
    if (k == 0) { s = -1.0f; oi = 0; }
    else { s = __uint_as_float(k); oi = (int)(~(u32)e); }
    score1[slice * K1_ + p] = s;
    idx1[slice * K1_ + p] = oi;
  }
}

// ---------------------------------------------------------------------------
// Kernel 2: per-(b,c) greedy NMS @ 0.4 over the sorted top-1000.
// ---------------------------------------------------------------------------
__global__ __launch_bounds__(256) void k_nms1(const float* __restrict__ boxes,
                                              const float* __restrict__ score1,
                                              const int* __restrict__ idx1,
                                              int* __restrict__ keep1) {
  const int slice = blockIdx.x;
  const int b = slice / C_;
  const int tid = threadIdx.x, bd = blockDim.x;

  __shared__ float sy1[K1_], sx1[K1_], sy2[K1_], sx2[K1_], sar[K1_];
  __shared__ u32 validw[32], suppw[32];
  if (tid < 32) { validw[tid] = 0; suppw[tid] = 0; }
  __syncthreads();

  for (int p = tid; p < K1_; p += bd) {
    float s = score1[slice * K1_ + p];
    bool v = (s >= MIN_CONF_F);
    float cx = 0.f, cy = 0.f, w = 0.f, h = 0.f;
    if (v) {
      int oi = idx1[slice * K1_ + p];
      const float* bp = boxes + ((size_t)b * N_ + oi) * 4;
      cx = bp[0]; cy = bp[1]; w = bp[2]; h = bp[3];
      atomicOr(&validw[p >> 5], 1u << (p & 31));
    }
    float y1 = cy - h * 0.5f, x1 = cx - w * 0.5f;
    float y2 = cy + h * 0.5f, x2 = cx + w * 0.5f;
    sy1[p] = y1; sx1[p] = x1; sy2[p] = y2; sx2[p] = x2;
    sar[p] = (y2 - y1) * (x2 - x1);
  }
  __syncthreads();

  for (int i = 0; i < K1_; ++i) {
    u32 bit = 1u << (i & 31);
    bool active = (validw[i >> 5] & bit) && !(suppw[i >> 5] & bit);
    if (!active) continue;
    float iy1 = sy1[i], ix1 = sx1[i], iy2 = sy2[i], ix2 = sx2[i], ia = sar[i];
    for (int j = i + 1 + tid; j < K1_; j += bd) {
      float ih = fminf(iy2, sy2[j]) - fmaxf(iy1, sy1[j]); ih = fmaxf(ih, 0.0f);
      float iw = fminf(ix2, sx2[j]) - fmaxf(ix1, sx1[j]); iw = fmaxf(iw, 0.0f);
      float inter = ih * iw;
      float uni = (ia + sar[j]) - inter;
      float iou = inter / fmaxf(uni, 1e-8f);
      if (iou > NMS_IOU_F) atomicOr(&suppw[j >> 5], 1u << (j & 31));
    }
    __syncthreads();
  }

  for (int p = tid; p < K1_; p += bd) {
    u32 bit = 1u << (p & 31);
    keep1[slice * K1_ + p] =
        ((validw[p >> 5] & bit) && !(suppw[p >> 5] & bit)) ? 1 : 0;
  }
}

// ---------------------------------------------------------------------------
// Kernel 3: per-batch top-1000 over the C*K1 survivors (stable, flat-index
// tie-break = lower class then lower slot).
// ---------------------------------------------------------------------------
__global__ __launch_bounds__(256) void k_topk2(const float* __restrict__ score1,
                                               const int* __restrict__ idx1,
                                               const int* __restrict__ keep1,
                                               float* __restrict__ sel_score,
                                               int* __restrict__ sel_cls,
                                               int* __restrict__ sel_orig) {
  const int b = blockIdx.x;
  const int tid = threadIdx.x, bd = blockDim.x;

  __shared__ u32 hist[NBIN];
  __shared__ u64 buf[CAP];
  __shared__ int sh_b1;
  __shared__ u32 sh_base, sh_T, sh_cnt;

  for (int i = tid; i < NBIN; i += bd) hist[i] = 0;
  __syncthreads();
  for (int f = tid; f < N2_; f += bd) {
    if (keep1[b * N2_ + f]) {
      u32 k = __float_as_uint(score1[b * N2_ + f]);
      atomicAdd(&hist[k >> 19], 1u);
    }
  }
  __syncthreads();
  if (tid == 0) {
    u32 cum = 0;
    int b1 = -1;
    u32 base = 0;
    for (int bin = NBIN - 1; bin >= 0; --bin) {
      cum += hist[bin];
      if (cum >= (u32)K1_) { b1 = bin; base = cum - hist[bin]; break; }
    }
    sh_b1 = b1;
    sh_base = base;
    if (b1 < 0) sh_T = 0;
  }
  __syncthreads();
  const int b1 = sh_b1;

  if (b1 >= 0) {
    const u32 base = sh_base;
    for (int i = tid; i < NBIN; i += bd) hist[i] = 0;
    __syncthreads();
    for (int f = tid; f < N2_; f += bd) {
      if (keep1[b * N2_ + f]) {
        u32 k = __float_as_uint(score1[b * N2_ + f]);
        if ((int)(k >> 19) == b1) atomicAdd(&hist[(k >> 7) & 0xFFFu], 1u);
      }
    }
    __syncthreads();
    if (tid == 0) {
      u32 cum = base;
      u32 T = ((u32)b1) << 19;
      for (int bin = NBIN - 1; bin >= 0; --bin) {
        cum += hist[bin];
        if (cum >= (u32)K1_) { T = (((u32)b1) << 19) | (((u32)bin) << 7); break; }
      }
      sh_T = T;
    }
    __syncthreads();
  }

  if (tid == 0) sh_cnt = 0;
  __syncthreads();
  const u32 T = sh_T;
  for (int f = tid; f < N2_; f += bd) {
    if (keep1[b * N2_ + f]) {
      u32 k = __float_as_uint(score1[b * N2_ + f]);
      if (k >= T) {
        u32 pos = atomicAdd(&sh_cnt, 1u);
        if (pos < CAP) buf[pos] = ((u64)k << 32) | (u32)(~(u32)f);
      }
    }
  }
  __syncthreads();
  u32 m = sh_cnt;
  if (m > CAP) m = CAP;
  for (int i = tid; i < CAP; i += bd)
    if ((u32)i >= m) buf[i] = 0ull;
  __syncthreads();

  for (u32 kk = 2; kk <= CAP; kk <<= 1) {
    for (u32 j = kk >> 1; j > 0; j >>= 1) {
      for (u32 i = tid; i < CAP; i += bd) {
        u32 l = i ^ j;
        if (l > i) {
          u64 a = buf[i], bb = buf[l];
          bool desc = ((i & kk) == 0);
          if (desc ? (a < bb) : (a > bb)) { buf[i] = bb; buf[l] = a; }
        }
      }
      __syncthreads();
    }
  }

  for (int p = tid; p < K1_; p += bd) {
    u64 e = buf[p];
    u32 k = (u32)(e >> 32);
    float s;
    int cls, orig;
    if (k == 0) { s = -1.0f; cls = 0; orig = 0; }
    else {
      s = __uint_as_float(k);
      u32 f = ~(u32)e;
      cls = (int)(f / K1_);
      int slot = (int)(f - (u32)cls * K1_);
      orig = idx1[(b * C_ + cls) * K1_ + slot];
    }
    sel_score[b * K1_ + p] = s;
    sel_cls[b * K1_ + p] = cls;
    sel_orig[b * K1_ + p] = orig;
  }
}

// ---------------------------------------------------------------------------
// Kernel 4: per-batch class-agnostic NMS @ 0.65, stable compaction of kept
// rows (== stable argsort of !keep), zero-fill, and final (8,1000,6) write.
// ---------------------------------------------------------------------------
__global__ __launch_bounds__(256) void k_nms2_out(const float* __restrict__ boxes,
                                                  const float* __restrict__ sel_score,
                                                  const int* __restrict__ sel_cls,
                                                  const int* __restrict__ sel_orig,
                                                  float* __restrict__ out) {
  const int b = blockIdx.x;
  const int tid = threadIdx.x, bd = blockDim.x;

  __shared__ float sy1[K1_], sx1[K1_], sy2[K1_], sx2[K1_], sar[K1_];
  __shared__ float rcx[K1_], rcy[K1_], rw[K1_], rh[K1_], rs[K1_];
  __shared__ int rcls[K1_];
  __shared__ u32 validw[32], suppw[32];
  __shared__ int ordc;
  __shared__ short ord[K1_];

  if (tid < 32) { validw[tid] = 0; suppw[tid] = 0; }
  __syncthreads();

  for (int p = tid; p < K1_; p += bd) {
    float s = sel_score[b * K1_ + p];
    bool v = (s >= MIN_CONF_F);
    int oi = sel_orig[b * K1_ + p];
    float cx = 0.f, cy = 0.f, w = 0.f, h = 0.f;
    if (v) {
      const float* bp = boxes + ((size_t)b * N_ + oi) * 4;
      cx = bp[0]; cy = bp[1]; w = bp[2]; h = bp[3];
      atomicOr(&validw[p >> 5], 1u << (p & 31));
    }
    float y1 = cy - h * 0.5f, x1 = cx - w * 0.5f;
    float y2 = cy + h * 0.5f, x2 = cx + w * 0.5f;
    sy1[p] = y1; sx1[p] = x1; sy2[p] = y2; sx2[p] = x2;
    sar[p] = (y2 - y1) * (x2 - x1);
    rcx[p] = cx; rcy[p] = cy; rw[p] = w; rh[p] = h;
    rs[p] = s;
    rcls[p] = sel_cls[b * K1_ + p];
  }
  __syncthreads();

  for (int i = 0; i < K1_; ++i) {
    u32 bit = 1u << (i & 31);
    bool active = (validw[i >> 5] & bit) && !(suppw[i >> 5] & bit);
    if (!active) continue;
    float iy1 = sy1[i], ix1 = sx1[i], iy2 = sy2[i], ix2 = sx2[i], ia = sar[i];
    for (int j = i + 1 + tid; j < K1_; j += bd) {
      float ih = fminf(iy2, sy2[j]) - fmaxf(iy1, sy1[j]); ih = fmaxf(ih, 0.0f);
      float iw = fminf(ix2, sx2[j]) - fmaxf(ix1, sx1[j]); iw = fmaxf(iw, 0.0f);
      float inter = ih * iw;
      float uni = (ia + sar[j]) - inter;
      float iou = inter / fmaxf(uni, 1e-8f);
      if (iou > POST_IOU_F) atomicOr(&suppw[j >> 5], 1u << (j & 31));
    }
    __syncthreads();
  }

  if (tid == 0) {
    int cnt = 0;
    for (int p = 0; p < K1_; ++p) {
      u32 bit = 1u << (p & 31);
      if ((validw[p >> 5] & bit) && !(suppw[p >> 5] & bit))
        ord[cnt++] = (short)p;
    }
    ordc = cnt;
  }
  __syncthreads();

  for (int t = tid; t < K1_ * 6; t += bd) out[(size_t)b * K1_ * 6 + t] = 0.0f;
  __syncthreads();

  const int cnt = ordc;
  for (int q = tid; q < cnt; q += bd) {
    int p = ord[q];
    float* o = out + ((size_t)b * K1_ + q) * 6;
    o[0] = rcx[p]; o[1] = rcy[p]; o[2] = rw[p]; o[3] = rh[p];
    o[4] = (float)rcls[p];
    o[5] = rs[p];
  }
}

// ---------------------------------------------------------------------------
extern "C" void kernel_launch(void* const* d_in, const int* in_sizes, int n_in,
                              void* d_out, int out_size, void* d_ws, size_t ws_size,
                              hipStream_t stream) {
  const float* cls = (const float*)d_in[0];    // (8,100000,10) f32
  const float* boxes = (const float*)d_in[1];  // (8,100000,4)  f32
  float* out = (float*)d_out;                  // (8,1000,6)    f32

  char* ws = (char*)d_ws;
  float* score1    = (float*)(ws);                     // 80000 f32
  int*   idx1      = (int*)(ws + 80000 * 4);           // 80000 i32
  int*   keep1     = (int*)(ws + 160000 * 4);          // 80000 i32
  float* sel_score = (float*)(ws + 240000 * 4);        // 8000 f32
  int*   sel_cls   = (int*)(ws + 248000 * 4);          // 8000 i32
  int*   sel_orig  = (int*)(ws + 256000 * 4);          // 8000 i32

  hipLaunchKernelGGL(k_topk1, dim3(B_ * C_), dim3(256), 0, stream,
                     cls, score1, idx1);
  hipLaunchKernelGGL(k_nms1, dim3(B_ * C_), dim3(256), 0, stream,
                     boxes, score1, idx1, keep1);
  hipLaunchKernelGGL(k_topk2, dim3(B_), dim3(256), 0, stream,
                     score1, idx1, keep1, sel_score, sel_cls, sel_orig);
  hipLaunchKernelGGL(k_nms2_out, dim3(B_), dim3(256), 0, stream,
                     boxes, sel_score, sel_cls, sel_orig, out);
}